// Round 6
// baseline (264.014 us; speedup 1.0000x reference)
//
#include <hip/hip_runtime.h>
#include <stdint.h>

typedef __attribute__((ext_vector_type(8))) short v8s;
typedef __attribute__((ext_vector_type(4))) short v4s;
typedef __attribute__((ext_vector_type(4))) float v4f;
typedef unsigned short u16;

#define EMB 1024
#define TOKS 4096
#define NSEQ 2048
#define NH 16
#define HD 64

__device__ __forceinline__ u16 f2bf(float f) {
    unsigned u = __builtin_bit_cast(unsigned, f);
    u += 0x7fffu + ((u >> 16) & 1u);
    return (u16)(u >> 16);
}
__device__ __forceinline__ float bf2f(u16 h) {
    unsigned u = ((unsigned)h) << 16;
    return __builtin_bit_cast(float, u);
}
__device__ __forceinline__ float exp2_fast(float x) {
#if __has_builtin(__builtin_amdgcn_exp2f)
    return __builtin_amdgcn_exp2f(x);   // compiler-managed v_exp_f32 (trans hazards handled)
#else
    return exp2f(x);
#endif
}

__device__ __forceinline__ void gll16(const void* g, void* l) {
    __builtin_amdgcn_global_load_lds(
        (const __attribute__((address_space(1))) unsigned int*)g,
        (__attribute__((address_space(3))) unsigned int*)l, 16, 0, 0);
}

// ---------------- convert x -> bf16 hi/lo ----------------
__global__ void k_convx(const float* __restrict__ x, u16* __restrict__ xhi, u16* __restrict__ xlo) {
    int i = (blockIdx.x * 256 + threadIdx.x) * 4;
    v4f v = *(const v4f*)(x + i);
    v4s h, l;
#pragma unroll
    for (int j = 0; j < 4; j++) {
        u16 hb = f2bf(v[j]);
        h[j] = (short)hb;
        l[j] = (short)f2bf(v[j] - bf2f(hb));
    }
    *(v4s*)(xhi + i) = h;
    *(v4s*)(xlo + i) = l;
}

// ---------------- transpose + split the 4 weights: wT[out][in] ----------------
__global__ void k_convw(const float* __restrict__ w0, const float* __restrict__ w1,
                        const float* __restrict__ w2, const float* __restrict__ w3,
                        u16* __restrict__ whiT, u16* __restrict__ wloT) {
    __shared__ float t[64][65];
    int z = blockIdx.z;
    const float* w = (z == 0) ? w0 : (z == 1) ? w1 : (z == 2) ? w2 : w3;
    int r0 = blockIdx.x * 64, c0 = blockIdx.y * 64;
    int tr = threadIdx.x >> 4, tc = (threadIdx.x & 15) * 4;
#pragma unroll
    for (int i = 0; i < 4; i++) {
        int row = tr + i * 16;
        v4f v = *(const v4f*)(w + (size_t)(r0 + row) * EMB + c0 + tc);
#pragma unroll
        for (int j = 0; j < 4; j++) t[row][tc + j] = v[j];
    }
    __syncthreads();
    u16* dh = whiT + (size_t)z * EMB * EMB;
    u16* dl = wloT + (size_t)z * EMB * EMB;
#pragma unroll
    for (int i = 0; i < 4; i++) {
        int orow = tr + i * 16;
        v4s h, l;
#pragma unroll
        for (int j = 0; j < 4; j++) {
            float f = t[tc + j][orow];
            u16 hb = f2bf(f);
            h[j] = (short)hb;
            l[j] = (short)f2bf(f - bf2f(hb));
        }
        size_t o = (size_t)(c0 + orow) * EMB + r0 + tc;
        *(v4s*)(dh + o) = h;
        *(v4s*)(dl + o) = l;
    }
}

// ---------------- split-bf16 GEMM: C[M=4096][N=1024] = A @ W + bias ----------------
// omode 0: z=0 -> Q (scaled by log2(e)/8), z=1 -> K, both [bh][n][d]; z=2 -> V^T [bh][d][n].
// omode 1: fp32 to outF.
__global__ __launch_bounds__(256, 2) void k_gemm(
    const u16* __restrict__ Ahi, const u16* __restrict__ Alo,
    const u16* __restrict__ Bhi0, const u16* __restrict__ Blo0,
    const float* __restrict__ b0, const float* __restrict__ b1, const float* __restrict__ b2,
    u16* __restrict__ outBF, u16* __restrict__ vT, float* __restrict__ outF, int omode) {
    __shared__ u16 sAh[128 * 32], sAl[128 * 32], sBh[128 * 32], sBl[128 * 32];
    int z = blockIdx.z;
    const u16* Bhi = Bhi0 + (size_t)z * EMB * EMB;
    const u16* Blo = Blo0 + (size_t)z * EMB * EMB;
    const float* bias = (z == 0) ? b0 : (z == 1) ? b1 : b2;
    // bijective XCD swizzle over the 256 (x,y) blocks
    int f = blockIdx.y * 32 + blockIdx.x;
    int fp = (f & 7) * 32 + (f >> 3);
    int m0 = (fp & 31) * 128, n0 = (fp >> 5) * 128;
    int tid = threadIdx.x, lane = tid & 63, warp = tid >> 6;
    int wm = warp >> 1, wn = warp & 1;
    int lr = lane & 15, lk = lane >> 4;
    int srow = lane >> 2;
    int sch = (lane & 3) ^ (srow & 3);
    int cAB = (lk ^ (lr & 3)) * 8;
    v4f z4 = {0.f, 0.f, 0.f, 0.f};
    v4f acc[4][4];
#pragma unroll
    for (int mi = 0; mi < 4; mi++)
#pragma unroll
        for (int ni = 0; ni < 4; ni++) acc[mi][ni] = z4;

    for (int k0 = 0; k0 < EMB; k0 += 32) {
#pragma unroll
        for (int ii = 0; ii < 2; ii++) {
            int it = warp * 2 + ii;
            int row = it * 16 + srow;
            size_t ga = (size_t)(m0 + row) * EMB + k0 + sch * 8;
            size_t gb = (size_t)(n0 + row) * EMB + k0 + sch * 8;
            gll16(&Ahi[ga], &sAh[it * 512]);
            gll16(&Alo[ga], &sAl[it * 512]);
            gll16(&Bhi[gb], &sBh[it * 512]);
            gll16(&Blo[gb], &sBl[it * 512]);
        }
        __syncthreads();
        v8s ah[4], al[4], bh[4], bl[4];
#pragma unroll
        for (int i = 0; i < 4; i++) {
            int ra = (wm * 64 + i * 16 + lr) * 32 + cAB;
            ah[i] = *(const v8s*)(&sAh[ra]);
            al[i] = *(const v8s*)(&sAl[ra]);
            int rb = (wn * 64 + i * 16 + lr) * 32 + cAB;
            bh[i] = *(const v8s*)(&sBh[rb]);
            bl[i] = *(const v8s*)(&sBl[rb]);
        }
#pragma unroll
        for (int mi = 0; mi < 4; mi++)
#pragma unroll
            for (int ni = 0; ni < 4; ni++) {
                acc[mi][ni] = __builtin_amdgcn_mfma_f32_16x16x32_bf16(ah[mi], bh[ni], acc[mi][ni], 0, 0, 0);
                acc[mi][ni] = __builtin_amdgcn_mfma_f32_16x16x32_bf16(al[mi], bh[ni], acc[mi][ni], 0, 0, 0);
                acc[mi][ni] = __builtin_amdgcn_mfma_f32_16x16x32_bf16(ah[mi], bl[ni], acc[mi][ni], 0, 0, 0);
            }
        __syncthreads();
    }
#pragma unroll
    for (int mi = 0; mi < 4; mi++) {
#pragma unroll
        for (int ni = 0; ni < 4; ni++) {
            int col = n0 + wn * 64 + ni * 16 + lr;
            float bv = bias[col];
#pragma unroll
            for (int r = 0; r < 4; r++) {
                int row = m0 + wm * 64 + mi * 16 + lk * 4 + r;
                float val = acc[mi][ni][r] + bv;
                if (omode == 0) {
                    int bb = row >> 11, nn = row & 2047, h = col >> 6, d = col & 63;
                    if (z == 2) {
                        size_t idx = ((size_t)(bb * NH + h) * HD + d) * NSEQ + nn;  // V^T [bh][d][n]
                        vT[idx] = f2bf(val);
                    } else {
                        if (z == 0) val *= 0.18033688011112042f;  // (1/8)*log2(e)
                        size_t idx = (((size_t)(bb * NH + h)) * NSEQ + nn) * HD + d;
                        (outBF + (size_t)z * TOKS * EMB)[idx] = f2bf(val);
                    }
                } else {
                    outF[(size_t)row * EMB + col] = val;
                }
            }
        }
    }
}

// ---------------- flash attention (R2-verified structure) ----------------
// Unswapped QK^T, per-wave P (verified swizzle), V from global V^T B-frags.
// Q,K: [32 bh][2048][64] bf16 (Q pre-scaled by log2(e)/8). Vt: [32 bh][64 d][2048 n].
__global__ __launch_bounds__(256, 2) void k_attn(
    const u16* __restrict__ Q, const u16* __restrict__ K, const u16* __restrict__ Vt,
    u16* __restrict__ Ohi, u16* __restrict__ Olo) {
    __shared__ u16 sK[2][4096];
    __shared__ u16 sP[4 * 1024];   // per-wave 16q x 64k
    int tid = threadIdx.x, lane = tid & 63, warp = tid >> 6;
    int lr = lane & 15, lk = lane >> 4;
    int bid = blockIdx.x;
    int qi = (bid >> 3) & 31;
    int bh = (bid & 7) | (((bid >> 8) & 3) << 3);  // bid%8 = XCD; 4 bh per XCD -> K/Vt L2-resident
    int q0 = qi * 64;
    const u16* Qb = Q + ((size_t)bh * NSEQ + q0 + warp * 16 + lr) * HD;
    v8s aq0 = *(const v8s*)(Qb + lk * 8);
    v8s aq1 = *(const v8s*)(Qb + 32 + lk * 8);
    v4f z4 = {0.f, 0.f, 0.f, 0.f};
    v4f oacc[4] = {z4, z4, z4, z4};
    float l_part[4] = {0.f, 0.f, 0.f, 0.f};
    const u16* Kb = K + (size_t)bh * NSEQ * HD;
    const u16* Vb = Vt + (size_t)bh * HD * NSEQ;   // [64 d][2048 n]
    int srow8 = lane >> 3, kc8 = lane & 7;

    // prologue: stage K tile 0 (pre-swizzled source -> linear LDS)
#pragma unroll
    for (int ii = 0; ii < 2; ii++) {
        int it = warp * 2 + ii;
        int row = it * 8 + srow8;
        int kc = kc8 ^ (row & 7);
        gll16(&Kb[(size_t)row * HD + kc * 8], &sK[0][it * 512]);
    }
    __syncthreads();

    u16* Pw = &sP[warp * 1024];
    for (int t = 0; t < 32; ++t) {
        int cur = t & 1;
        if (t < 31) {
#pragma unroll
            for (int ii = 0; ii < 2; ii++) {
                int it = warp * 2 + ii;
                int row = it * 8 + srow8;
                int kc = kc8 ^ (row & 7);
                gll16(&Kb[(size_t)((t + 1) * 64 + row) * HD + kc * 8], &sK[cur ^ 1][it * 512]);
            }
        }
        // S = Q K^T (wave's 16 q-rows x 64 keys); s already includes log2e/8 via Q
        v4f sacc[4];
#pragma unroll
        for (int ni = 0; ni < 4; ni++) {
            int rowb = (ni * 16 + lr) * 64;
            v8s kb0 = *(const v8s*)(&sK[cur][rowb + ((lk ^ (lr & 7)) * 8)]);
            v8s kb1 = *(const v8s*)(&sK[cur][rowb + (((4 + lk) ^ (lr & 7)) * 8)]);
            v4f a = z4;
            a = __builtin_amdgcn_mfma_f32_16x16x32_bf16(aq0, kb0, a, 0, 0, 0);
            a = __builtin_amdgcn_mfma_f32_16x16x32_bf16(aq1, kb1, a, 0, 0, 0);
            sacc[ni] = a;
        }
        // p = exp2(s); per-lane partial l; P -> per-wave LDS (verified swizzle)
#pragma unroll
        for (int ni = 0; ni < 4; ni++) {
            int colh = ni * 16 + lr;
#pragma unroll
            for (int r = 0; r < 4; r++) {
                float p = exp2_fast(sacc[ni][r]);
                l_part[r] += p;
                int rr = lk * 4 + r;
                Pw[rr * 64 + (((colh >> 3) ^ (rr & 7)) * 8) + (colh & 7)] = f2bf(p);
            }
        }
        // O += P V : P from same-wave LDS (in-order DS), V from global V^T (L2)
        v8s pa0 = *(const v8s*)(&Pw[lr * 64 + ((lk ^ (lr & 7)) * 8)]);
        v8s pa1 = *(const v8s*)(&Pw[lr * 64 + (((4 + lk) ^ (lr & 7)) * 8)]);
#pragma unroll
        for (int dt = 0; dt < 4; dt++) {
            const u16* vr = Vb + (size_t)(dt * 16 + lr) * NSEQ + t * 64;
            v8s vb0 = *(const v8s*)(vr + lk * 8);
            v8s vb1 = *(const v8s*)(vr + 32 + lk * 8);
            oacc[dt] = __builtin_amdgcn_mfma_f32_16x16x32_bf16(pa0, vb0, oacc[dt], 0, 0, 0);
            oacc[dt] = __builtin_amdgcn_mfma_f32_16x16x32_bf16(pa1, vb1, oacc[dt], 0, 0, 0);
        }
        __syncthreads();  // protects sK[cur] before t+1 re-stages it
    }
    // deferred l: sum over the 16 lanes sharing lk (keys ni*16+lr covered per lane)
#pragma unroll
    for (int off = 1; off < 16; off <<= 1)
#pragma unroll
        for (int r = 0; r < 4; r++) l_part[r] += __shfl_xor(l_part[r], off);
    int bb = bh >> 4, h = bh & 15;
#pragma unroll
    for (int r = 0; r < 4; r++) {
        float inv = 1.f / l_part[r];
        int tok = bb * NSEQ + q0 + warp * 16 + lk * 4 + r;
#pragma unroll
        for (int dt = 0; dt < 4; dt++) {
            float val = oacc[dt][r] * inv;
            size_t idx = (size_t)tok * EMB + h * 64 + dt * 16 + lr;
            u16 hb = f2bf(val);
            Ohi[idx] = hb;
            Olo[idx] = f2bf(val - bf2f(hb));
        }
    }
}

extern "C" void kernel_launch(void* const* d_in, const int* in_sizes, int n_in,
                              void* d_out, int out_size, void* d_ws, size_t ws_size,
                              hipStream_t stream) {
    const float* x  = (const float*)d_in[0];
    const float* wq = (const float*)d_in[1];
    const float* bq = (const float*)d_in[2];
    const float* wk = (const float*)d_in[3];
    const float* bk = (const float*)d_in[4];
    const float* wv = (const float*)d_in[5];
    const float* bv = (const float*)d_in[6];
    const float* wo = (const float*)d_in[7];
    const float* bo = (const float*)d_in[8];

    char* W = (char*)d_ws;
    u16* xhi  = (u16*)(W);
    u16* xlo  = (u16*)(W + 8388608);
    u16* wThi = (u16*)(W + 16777216);
    u16* wTlo = (u16*)(W + 25165824);
    u16* qkv  = (u16*)(W + 33554432);   // Q, K: [32][2048][64]; V^T: [32][64][2048]
    u16* Ohi  = (u16*)(W + 58720256);
    u16* Olo  = (u16*)(W + 67108864);

    u16* Qp = qkv;
    u16* Kp = qkv + 4194304;
    u16* Vtp = qkv + 8388608;

    k_convx<<<4096, 256, 0, stream>>>(x, xhi, xlo);
    k_convw<<<dim3(16, 16, 4), 256, 0, stream>>>(wq, wk, wv, wo, wThi, wTlo);
    k_gemm<<<dim3(32, 8, 3), 256, 0, stream>>>(xhi, xlo, wThi, wTlo, bq, bk, bv,
                                               qkv, Vtp, nullptr, 0);
    k_attn<<<dim3(1024), 256, 0, stream>>>(Qp, Kp, Vtp, Ohi, Olo);
    k_gemm<<<dim3(32, 8, 1), 256, 0, stream>>>(Ohi, Olo,
                                               wThi + 3 * 1048576, wTlo + 3 * 1048576,
                                               bo, bo, bo, nullptr, nullptr, (float*)d_out, 1);
}

// Round 7
// 198.416 us; speedup vs baseline: 1.3306x; 1.3306x over previous
//
#include <hip/hip_runtime.h>
#include <stdint.h>

typedef __attribute__((ext_vector_type(8))) short v8s;
typedef __attribute__((ext_vector_type(4))) short v4s;
typedef __attribute__((ext_vector_type(4))) float v4f;
typedef unsigned short u16;

#define EMB 1024
#define TOKS 4096
#define NSEQ 2048
#define NH 16
#define HD 64

__device__ __forceinline__ u16 f2bf(float f) {
    unsigned u = __builtin_bit_cast(unsigned, f);
    u += 0x7fffu + ((u >> 16) & 1u);
    return (u16)(u >> 16);
}
__device__ __forceinline__ float bf2f(u16 h) {
    unsigned u = ((unsigned)h) << 16;
    return __builtin_bit_cast(float, u);
}
__device__ __forceinline__ float exp2_fast(float x) {
#if __has_builtin(__builtin_amdgcn_exp2f)
    return __builtin_amdgcn_exp2f(x);   // compiler-managed v_exp_f32 (trans hazards handled)
#else
    return exp2f(x);
#endif
}

__device__ __forceinline__ void gll16(const void* g, void* l) {
    __builtin_amdgcn_global_load_lds(
        (const __attribute__((address_space(1))) unsigned int*)g,
        (__attribute__((address_space(3))) unsigned int*)l, 16, 0, 0);
}

// ---------------- convert x -> bf16 hi/lo ----------------
__global__ void k_convx(const float* __restrict__ x, u16* __restrict__ xhi, u16* __restrict__ xlo) {
    int i = (blockIdx.x * 256 + threadIdx.x) * 4;
    v4f v = *(const v4f*)(x + i);
    v4s h, l;
#pragma unroll
    for (int j = 0; j < 4; j++) {
        u16 hb = f2bf(v[j]);
        h[j] = (short)hb;
        l[j] = (short)f2bf(v[j] - bf2f(hb));
    }
    *(v4s*)(xhi + i) = h;
    *(v4s*)(xlo + i) = l;
}

// ---------------- transpose + split the 4 weights: wT[out][in] ----------------
__global__ void k_convw(const float* __restrict__ w0, const float* __restrict__ w1,
                        const float* __restrict__ w2, const float* __restrict__ w3,
                        u16* __restrict__ whiT, u16* __restrict__ wloT) {
    __shared__ float t[64][65];
    int z = blockIdx.z;
    const float* w = (z == 0) ? w0 : (z == 1) ? w1 : (z == 2) ? w2 : w3;
    int r0 = blockIdx.x * 64, c0 = blockIdx.y * 64;
    int tr = threadIdx.x >> 4, tc = (threadIdx.x & 15) * 4;
#pragma unroll
    for (int i = 0; i < 4; i++) {
        int row = tr + i * 16;
        v4f v = *(const v4f*)(w + (size_t)(r0 + row) * EMB + c0 + tc);
#pragma unroll
        for (int j = 0; j < 4; j++) t[row][tc + j] = v[j];
    }
    __syncthreads();
    u16* dh = whiT + (size_t)z * EMB * EMB;
    u16* dl = wloT + (size_t)z * EMB * EMB;
#pragma unroll
    for (int i = 0; i < 4; i++) {
        int orow = tr + i * 16;
        v4s h, l;
#pragma unroll
        for (int j = 0; j < 4; j++) {
            float f = t[tc + j][orow];
            u16 hb = f2bf(f);
            h[j] = (short)hb;
            l[j] = (short)f2bf(f - bf2f(hb));
        }
        size_t o = (size_t)(c0 + orow) * EMB + r0 + tc;
        *(v4s*)(dh + o) = h;
        *(v4s*)(dl + o) = l;
    }
}

// ---------------- split-bf16 GEMM: C[M=4096][N=1024] = A @ W + bias ----------------
// omode 0: z=0 -> Q (scaled by log2(e)/8), z=1 -> K, both [bh][n][d]; z=2 -> V^T [bh][d][n].
// omode 1: fp32 to outF.
__global__ __launch_bounds__(256, 2) void k_gemm(
    const u16* __restrict__ Ahi, const u16* __restrict__ Alo,
    const u16* __restrict__ Bhi0, const u16* __restrict__ Blo0,
    const float* __restrict__ b0, const float* __restrict__ b1, const float* __restrict__ b2,
    u16* __restrict__ outBF, u16* __restrict__ vT, float* __restrict__ outF, int omode) {
    __shared__ u16 sAh[128 * 32], sAl[128 * 32], sBh[128 * 32], sBl[128 * 32];
    int z = blockIdx.z;
    const u16* Bhi = Bhi0 + (size_t)z * EMB * EMB;
    const u16* Blo = Blo0 + (size_t)z * EMB * EMB;
    const float* bias = (z == 0) ? b0 : (z == 1) ? b1 : b2;
    // bijective XCD swizzle over the 256 (x,y) blocks
    int f = blockIdx.y * 32 + blockIdx.x;
    int fp = (f & 7) * 32 + (f >> 3);
    int m0 = (fp & 31) * 128, n0 = (fp >> 5) * 128;
    int tid = threadIdx.x, lane = tid & 63, warp = tid >> 6;
    int wm = warp >> 1, wn = warp & 1;
    int lr = lane & 15, lk = lane >> 4;
    int srow = lane >> 2;
    int sch = (lane & 3) ^ (srow & 3);
    int cAB = (lk ^ (lr & 3)) * 8;
    v4f z4 = {0.f, 0.f, 0.f, 0.f};
    v4f acc[4][4];
#pragma unroll
    for (int mi = 0; mi < 4; mi++)
#pragma unroll
        for (int ni = 0; ni < 4; ni++) acc[mi][ni] = z4;

    for (int k0 = 0; k0 < EMB; k0 += 32) {
#pragma unroll
        for (int ii = 0; ii < 2; ii++) {
            int it = warp * 2 + ii;
            int row = it * 16 + srow;
            size_t ga = (size_t)(m0 + row) * EMB + k0 + sch * 8;
            size_t gb = (size_t)(n0 + row) * EMB + k0 + sch * 8;
            gll16(&Ahi[ga], &sAh[it * 512]);
            gll16(&Alo[ga], &sAl[it * 512]);
            gll16(&Bhi[gb], &sBh[it * 512]);
            gll16(&Blo[gb], &sBl[it * 512]);
        }
        __syncthreads();
        v8s ah[4], al[4], bh[4], bl[4];
#pragma unroll
        for (int i = 0; i < 4; i++) {
            int ra = (wm * 64 + i * 16 + lr) * 32 + cAB;
            ah[i] = *(const v8s*)(&sAh[ra]);
            al[i] = *(const v8s*)(&sAl[ra]);
            int rb = (wn * 64 + i * 16 + lr) * 32 + cAB;
            bh[i] = *(const v8s*)(&sBh[rb]);
            bl[i] = *(const v8s*)(&sBl[rb]);
        }
#pragma unroll
        for (int mi = 0; mi < 4; mi++)
#pragma unroll
            for (int ni = 0; ni < 4; ni++) {
                acc[mi][ni] = __builtin_amdgcn_mfma_f32_16x16x32_bf16(ah[mi], bh[ni], acc[mi][ni], 0, 0, 0);
                acc[mi][ni] = __builtin_amdgcn_mfma_f32_16x16x32_bf16(al[mi], bh[ni], acc[mi][ni], 0, 0, 0);
                acc[mi][ni] = __builtin_amdgcn_mfma_f32_16x16x32_bf16(ah[mi], bl[ni], acc[mi][ni], 0, 0, 0);
            }
        __syncthreads();
    }
#pragma unroll
    for (int mi = 0; mi < 4; mi++) {
#pragma unroll
        for (int ni = 0; ni < 4; ni++) {
            int col = n0 + wn * 64 + ni * 16 + lr;
            float bv = bias[col];
#pragma unroll
            for (int r = 0; r < 4; r++) {
                int row = m0 + wm * 64 + mi * 16 + lk * 4 + r;
                float val = acc[mi][ni][r] + bv;
                if (omode == 0) {
                    int bb = row >> 11, nn = row & 2047, h = col >> 6, d = col & 63;
                    if (z == 2) {
                        size_t idx = ((size_t)(bb * NH + h) * HD + d) * NSEQ + nn;  // V^T [bh][d][n]
                        vT[idx] = f2bf(val);
                    } else {
                        if (z == 0) val *= 0.18033688011112042f;  // (1/8)*log2(e)
                        size_t idx = (((size_t)(bb * NH + h)) * NSEQ + nn) * HD + d;
                        (outBF + (size_t)z * TOKS * EMB)[idx] = f2bf(val);
                    }
                } else {
                    outF[(size_t)row * EMB + col] = val;
                }
            }
        }
    }
}

// ---------------- flash attention: 128-q blocks, K and V^T staged via global_load_lds ----------------
// Q,K: [32 bh][2048][64] bf16 (Q pre-scaled by log2(e)/8). Vt: [32 bh][64 d][2048 n].
// Block: 128 q-rows, 4 waves x 32 q-rows. Per tile: stage K(64x64) + VT(64x64), 1 barrier.
__global__ __launch_bounds__(256, 2) void k_attn(
    const u16* __restrict__ Q, const u16* __restrict__ K, const u16* __restrict__ Vt,
    u16* __restrict__ Ohi, u16* __restrict__ Olo) {
    __shared__ u16 sK[2][4096];
    __shared__ u16 sVT[2][4096];
    __shared__ u16 sP[4 * 2048];   // per-wave 32q x 64k
    int tid = threadIdx.x, lane = tid & 63, w = tid >> 6;
    int lr = lane & 15, lk = lane >> 4;
    int bid = blockIdx.x;
    int qi = (bid >> 3) & 15;
    int bh = (bid & 7) | (((bid >> 7) & 3) << 3);  // bid%8 = XCD; 4 bh/XCD -> K,Vt L2-resident
    int q0 = qi * 128;

    // Q fragments: qb in {0,1}, rows q0 + w*32 + qb*16 + lr
    v8s aq[2][2];
#pragma unroll
    for (int qb = 0; qb < 2; qb++) {
        const u16* Qb = Q + ((size_t)bh * NSEQ + q0 + w * 32 + qb * 16 + lr) * HD;
        aq[qb][0] = *(const v8s*)(Qb + lk * 8);
        aq[qb][1] = *(const v8s*)(Qb + 32 + lk * 8);
    }
    const u16* Kb = K + (size_t)bh * NSEQ * HD;
    const u16* Vtb = Vt + (size_t)bh * HD * NSEQ;
    v4f z4 = {0.f, 0.f, 0.f, 0.f};
    v4f oacc[2][4];
#pragma unroll
    for (int qb = 0; qb < 2; qb++)
#pragma unroll
        for (int dt = 0; dt < 4; dt++) oacc[qb][dt] = z4;
    float l_part[2][4] = {{0.f, 0.f, 0.f, 0.f}, {0.f, 0.f, 0.f, 0.f}};
    int srow8 = lane >> 3, kc8 = lane & 7;

    // prologue: stage tile 0 (K rows: n; VT rows: d) with pre-swizzled source chunks
#pragma unroll
    for (int ii = 0; ii < 2; ii++) {
        int it = w * 2 + ii;
        int row = it * 8 + srow8;
        int kc = kc8 ^ (row & 7);
        gll16(&Kb[(size_t)row * HD + kc * 8], &sK[0][it * 512]);
        gll16(&Vtb[(size_t)row * NSEQ + kc * 8], &sVT[0][it * 512]);
    }
    __syncthreads();

    u16* Pw = &sP[w * 2048];
    for (int t = 0; t < 32; ++t) {
        int cur = t & 1;
        if (t < 31) {
#pragma unroll
            for (int ii = 0; ii < 2; ii++) {
                int it = w * 2 + ii;
                int row = it * 8 + srow8;
                int kc = kc8 ^ (row & 7);
                gll16(&Kb[(size_t)((t + 1) * 64 + row) * HD + kc * 8], &sK[cur ^ 1][it * 512]);
                gll16(&Vtb[(size_t)row * NSEQ + (t + 1) * 64 + kc * 8], &sVT[cur ^ 1][it * 512]);
            }
        }
        // S = Q K^T for both q-groups (sacc[qb][ni][r] = S[q0+w*32+qb*16+lk*4+r][t*64+ni*16+lr])
        v4f sacc[2][4];
#pragma unroll
        for (int ni = 0; ni < 4; ni++) {
            int rowb = (ni * 16 + lr) * 64;
            v8s kb0 = *(const v8s*)(&sK[cur][rowb + ((lk ^ (lr & 7)) * 8)]);
            v8s kb1 = *(const v8s*)(&sK[cur][rowb + (((4 + lk) ^ (lr & 7)) * 8)]);
#pragma unroll
            for (int qb = 0; qb < 2; qb++) {
                v4f a = z4;
                a = __builtin_amdgcn_mfma_f32_16x16x32_bf16(aq[qb][0], kb0, a, 0, 0, 0);
                a = __builtin_amdgcn_mfma_f32_16x16x32_bf16(aq[qb][1], kb1, a, 0, 0, 0);
                sacc[qb][ni] = a;
            }
        }
        // p = exp2(s); per-lane partial l; P -> per-wave LDS (verified swizzle, rows qb*16+lk*4+r)
#pragma unroll
        for (int qb = 0; qb < 2; qb++)
#pragma unroll
            for (int ni = 0; ni < 4; ni++) {
                int colh = ni * 16 + lr;
#pragma unroll
                for (int r = 0; r < 4; r++) {
                    float p = exp2_fast(sacc[qb][ni][r]);
                    l_part[qb][r] += p;
                    int rr = qb * 16 + lk * 4 + r;
                    Pw[rr * 64 + (((colh >> 3) ^ (rr & 7)) * 8) + (colh & 7)] = f2bf(p);
                }
            }
        // O += P V : P A-frags (same-wave LDS), V B-frags from staged sVT
        v8s pa0[2], pa1[2];
#pragma unroll
        for (int qb = 0; qb < 2; qb++) {
            int prow = (qb * 16 + lr) * 64;
            pa0[qb] = *(const v8s*)(&Pw[prow + ((lk ^ (lr & 7)) * 8)]);
            pa1[qb] = *(const v8s*)(&Pw[prow + (((4 + lk) ^ (lr & 7)) * 8)]);
        }
#pragma unroll
        for (int dt = 0; dt < 4; dt++) {
            int rowb = (dt * 16 + lr) * 64;
            v8s vb0 = *(const v8s*)(&sVT[cur][rowb + ((lk ^ (lr & 7)) * 8)]);
            v8s vb1 = *(const v8s*)(&sVT[cur][rowb + (((4 + lk) ^ (lr & 7)) * 8)]);
#pragma unroll
            for (int qb = 0; qb < 2; qb++) {
                oacc[qb][dt] = __builtin_amdgcn_mfma_f32_16x16x32_bf16(pa0[qb], vb0, oacc[qb][dt], 0, 0, 0);
                oacc[qb][dt] = __builtin_amdgcn_mfma_f32_16x16x32_bf16(pa1[qb], vb1, oacc[qb][dt], 0, 0, 0);
            }
        }
        __syncthreads();  // sK/sVT[cur] safe to re-stage; also drains next-tile DMA queue
    }
    // deferred l: sum over the 16 lanes sharing lk
#pragma unroll
    for (int off = 1; off < 16; off <<= 1)
#pragma unroll
        for (int qb = 0; qb < 2; qb++)
#pragma unroll
            for (int r = 0; r < 4; r++) l_part[qb][r] += __shfl_xor(l_part[qb][r], off);
    int bb = bh >> 4, h = bh & 15;
#pragma unroll
    for (int qb = 0; qb < 2; qb++)
#pragma unroll
        for (int r = 0; r < 4; r++) {
            float inv = 1.f / l_part[qb][r];
            int tok = bb * NSEQ + q0 + w * 32 + qb * 16 + lk * 4 + r;
#pragma unroll
            for (int dt = 0; dt < 4; dt++) {
                float val = oacc[qb][dt][r] * inv;
                size_t idx = (size_t)tok * EMB + h * 64 + dt * 16 + lr;
                u16 hb = f2bf(val);
                Ohi[idx] = hb;
                Olo[idx] = f2bf(val - bf2f(hb));
            }
        }
}

extern "C" void kernel_launch(void* const* d_in, const int* in_sizes, int n_in,
                              void* d_out, int out_size, void* d_ws, size_t ws_size,
                              hipStream_t stream) {
    const float* x  = (const float*)d_in[0];
    const float* wq = (const float*)d_in[1];
    const float* bq = (const float*)d_in[2];
    const float* wk = (const float*)d_in[3];
    const float* bk = (const float*)d_in[4];
    const float* wv = (const float*)d_in[5];
    const float* bv = (const float*)d_in[6];
    const float* wo = (const float*)d_in[7];
    const float* bo = (const float*)d_in[8];

    char* W = (char*)d_ws;
    u16* xhi  = (u16*)(W);
    u16* xlo  = (u16*)(W + 8388608);
    u16* wThi = (u16*)(W + 16777216);
    u16* wTlo = (u16*)(W + 25165824);
    u16* qkv  = (u16*)(W + 33554432);   // Q, K: [32][2048][64]; V^T: [32][64][2048]
    u16* Ohi  = (u16*)(W + 58720256);
    u16* Olo  = (u16*)(W + 67108864);

    u16* Qp = qkv;
    u16* Kp = qkv + 4194304;
    u16* Vtp = qkv + 8388608;

    k_convx<<<4096, 256, 0, stream>>>(x, xhi, xlo);
    k_convw<<<dim3(16, 16, 4), 256, 0, stream>>>(wq, wk, wv, wo, wThi, wTlo);
    k_gemm<<<dim3(32, 8, 3), 256, 0, stream>>>(xhi, xlo, wThi, wTlo, bq, bk, bv,
                                               qkv, Vtp, nullptr, 0);
    k_attn<<<dim3(512), 256, 0, stream>>>(Qp, Kp, Vtp, Ohi, Olo);
    k_gemm<<<dim3(32, 8, 1), 256, 0, stream>>>(Ohi, Olo,
                                               wThi + 3 * 1048576, wTlo + 3 * 1048576,
                                               bo, bo, bo, nullptr, nullptr, (float*)d_out, 1);
}